// Round 1
// baseline (173.917 us; speedup 1.0000x reference)
//
#include <hip/hip_runtime.h>

#define CAR 8
#define SROW 520   // CAR + 64*CAR
#define HID 256
#define EOUT 257
#define XPAD 288   // padded Q-input row: 8 self + 257 enc + pad, 9 k-steps of 32
#define ADIM 30

typedef __attribute__((ext_vector_type(8))) short sh8;
typedef __attribute__((ext_vector_type(4))) float f32x4;

__device__ __forceinline__ short f2bf(float f) {
  unsigned u = __builtin_bit_cast(unsigned, f);
  u += 0x7fffu + ((u >> 16) & 1u);   // RNE
  return (short)(u >> 16);
}
// pack two fp32 -> packed bf16x2 (RNE, 5 VALU)
__device__ __forceinline__ unsigned f2bf2(float a, float b) {
  unsigned ua = __builtin_bit_cast(unsigned, a);
  ua += 0x7fffu + ((ua >> 16) & 1u);
  unsigned ub = __builtin_bit_cast(unsigned, b);
  ub += 0x7fffu + ((ub >> 16) & 1u);
  return __builtin_amdgcn_perm(ub, ua, 0x07060302);  // [a.hi16 | b.hi16]
}
// pack two fp32 -> packed bf16x2 (TRUNC, 1 VALU) — used for h staging only
__device__ __forceinline__ unsigned pkt(float a, float b) {
  return __builtin_amdgcn_perm(__builtin_bit_cast(unsigned, b),
                               __builtin_bit_cast(unsigned, a), 0x07060302);
}

// ---------------------------------------------------------------------------
// Prep: swizzle all weights to bf16 MFMA fragments. (unchanged)
// w1f : [W1;b1]^T as A [16 mt][64][8]  k=0..7 -> W1 row, k=8 -> b1   (8192)
// w2f : W2  as B   [8 ks][17 nt][64][8]               (69632)  stride/ks = 8704!
// w3f : Qw1 as B   [9 ks][16 nt][64][8], k=X-row idx  (73728)
// wq2f: Qw2 as B   [8 ks][2 nt][64][8]                (8192)
// ---------------------------------------------------------------------------
__global__ void k_prep(const float* __restrict__ W1, const float* __restrict__ b1,
                       const float* __restrict__ W2,
                       const float* __restrict__ Qw1, const float* __restrict__ Qw2,
                       short* __restrict__ w1f, short* __restrict__ w2f,
                       short* __restrict__ w3f, short* __restrict__ wq2f) {
  int idx = blockIdx.x * 256 + threadIdx.x;
  if (idx < 8192) {                         // [W1;b1]^T as A
    int mt = idx >> 9, r = idx & 511, lane = r >> 3, j = r & 7;
    int quad = lane >> 4, m = lane & 15;
    int hid = mt * 16 + m;
    float v = (quad == 0) ? W1[j * HID + hid]
            : (quad == 1 && j == 0) ? b1[hid] : 0.0f;   // k=8 row = b1
    w1f[idx] = f2bf(v);
    return;
  }
  int i2 = idx - 8192;
  if (i2 < 69632) {                         // W2 as B (ks stride = 17*512 = 8704)
    int ks = i2 / 8704, r = i2 % 8704;
    int nt = r >> 9, r2 = r & 511, lane = r2 >> 3, j = r2 & 7;
    int quad = lane >> 4, m = lane & 15;
    int k = ks * 32 + quad * 8 + j, n = nt * 16 + m;
    float v = (n < EOUT) ? W2[k * EOUT + n] : 0.0f;
    w2f[i2] = f2bf(v);
    return;
  }
  int i3 = i2 - 69632;
  if (i3 < 73728) {                         // Qw1 as B (k indexes padded X row)
    int ks = i3 >> 13, r = i3 & 8191;
    int nt = r >> 9, r2 = r & 511, lane = r2 >> 3, j = r2 & 7;
    int quad = lane >> 4, m = lane & 15;
    int k = ks * 32 + quad * 8 + j, n = nt * 16 + m;
    float v = (k < 265) ? Qw1[k * HID + n] : 0.0f;
    w3f[i3] = f2bf(v);
    return;
  }
  int i4 = i3 - 73728;
  if (i4 < 8192) {                          // Qw2 as B
    int ks = i4 >> 10, r = i4 & 1023;
    int nt = r >> 9, r2 = r & 511, lane = r2 >> 3, j = r2 & 7;
    int quad = lane >> 4, m = lane & 15;
    int k = ks * 32 + quad * 8 + j, n = nt * 16 + m;
    float v = (n < ADIM) ? Qw2[k * ADIM + n] : 0.0f;
    wq2f[i4] = f2bf(v);
  }
}

// ---------------------------------------------------------------------------
// K1: fused encoder + pool. NB=1 batch elem per block, 4 waves.
// LDS 32.3 KB + reg-lean (acc 4x4 + 1 tile16 frag) -> __launch_bounds__(256,4)
// targets 4 blocks/CU (occupancy was the bottleneck: 18%, both pipes ~40%).
// Wave w: phase 1 computes h for agents 16w..16w+15 (all 256 hid);
// phase 2 computes nt tiles {4w..4w+3} over all 64 agents PLUS tile 16 for its
// own agent group (1 MFMA/ks) -> perfectly balanced 136 MFMA/wave; tile-16
// pooled partials cross-wave summed via a 4x16 LDS buffer.
// ---------------------------------------------------------------------------
__global__ __launch_bounds__(256, 4)
void k_enc(const float* __restrict__ s, const short* __restrict__ w1f,
           const short* __restrict__ w2f, const float* __restrict__ b2,
           float* __restrict__ so288, int B) {
  __shared__ __align__(16) short hlds[16384];  // 32 KB: [(T*8+ks)*64+slot]*8+j
  __shared__ float ninvp[4];
  __shared__ float t16[4][16];

  const int tid = threadIdx.x;
  const int w = tid >> 6, lane = tid & 63;
  const int q = lane >> 4, m = lane & 15;
  const size_t bg = blockIdx.x;              // one elem per block

  // ---- phase 1: h = relu([surr,1]@[W1;b1]), mask folded into B operand ----
  const float* srow0 = s + bg * SROW + CAR;
  int4 pk = {0, 0, 0, 0};
  bool inv = false;
  if (lane < 16) {                           // agent = 16*w + lane
    const float* sr = srow0 + (w * 16 + lane) * CAR;
    float4 f0 = ((const float4*)sr)[0], f1 = ((const float4*)sr)[1];
    inv = (f0.x == -1.f) | (f0.y == -1.f) | (f0.z == -1.f) | (f0.w == -1.f) |
          (f1.x == -1.f) | (f1.y == -1.f) | (f1.z == -1.f) | (f1.w == -1.f);
    if (!inv) {                              // mask folded at source
      pk.x = (int)f2bf2(f0.x, f0.y); pk.y = (int)f2bf2(f0.z, f0.w);
      pk.z = (int)f2bf2(f1.x, f1.y); pk.w = (int)f2bf2(f1.z, f1.w);
    }
  }
  const float vflag = inv ? 0.f : 1.f;
  unsigned long long bal = __ballot(inv);
  if (lane == 0) ninvp[w] = (float)__popcll(bal);

  if (w == 1) {                              // self-state + tail pad
    if (lane < CAR)       so288[bg * XPAD + lane] = s[bg * SROW + lane];
    else if (lane < 16)   so288[bg * XPAD + 280 + (lane - 8)] = 0.f;
  }

  int4 p0;
  p0.x = __shfl(pk.x, m, 64); p0.y = __shfl(pk.y, m, 64);
  p0.z = __shfl(pk.z, m, 64); p0.w = __shfl(pk.w, m, 64);
  const float vv0 = __shfl(vflag, m, 64);
  if (q == 1) {                              // k=8 constant-1 column (masked)
    p0.x = (vv0 != 0.f) ? 0x3f80 : 0; p0.y = p0.z = p0.w = 0;
  } else if (q >= 2) {
    p0.x = p0.y = p0.z = p0.w = 0;
  }
  sh8 bs = __builtin_bit_cast(sh8, p0);

#pragma unroll 4
  for (int mt = 0; mt < 16; ++mt) {
    sh8 af = *(const sh8*)(w1f + (mt * 64 + lane) * 8);
    f32x4 z = {0.f, 0.f, 0.f, 0.f};
    f32x4 c0 = __builtin_amdgcn_mfma_f32_16x16x32_bf16(af, bs, z, 0, 0, 0);
    const int hidb = mt * 16 + q * 4;
    const int ks = hidb >> 5, qB = (hidb >> 3) & 3, js = hidb & 7;
    uint2 k0;
    k0.x = pkt(fmaxf(c0[0], 0.f), fmaxf(c0[1], 0.f));
    k0.y = pkt(fmaxf(c0[2], 0.f), fmaxf(c0[3], 0.f));
    *(uint2*)(&hlds[((w * 8 + ks) * 64 + qB * 16 + m) * 8 + js]) = k0;
  }
  __syncthreads();

  // ---- phase 2: enc = h @ W2 ----
  f32x4 acc[4][4];
  f32x4 acc16 = {0.f, 0.f, 0.f, 0.f};
#pragma unroll
  for (int mtA = 0; mtA < 4; ++mtA)
#pragma unroll
    for (int i = 0; i < 4; ++i) {
      f32x4 z = {0.f, 0.f, 0.f, 0.f};
      acc[mtA][i] = z;
    }
  const int t0 = 4 * w;
#pragma unroll 2
  for (int ks = 0; ks < 8; ++ks) {
    sh8 A0 = *(const sh8*)(&hlds[((0 * 8 + ks) * 64 + lane) * 8]);
    sh8 A1 = *(const sh8*)(&hlds[((1 * 8 + ks) * 64 + lane) * 8]);
    sh8 A2 = *(const sh8*)(&hlds[((2 * 8 + ks) * 64 + lane) * 8]);
    sh8 A3 = *(const sh8*)(&hlds[((3 * 8 + ks) * 64 + lane) * 8]);
    sh8 A16 = *(const sh8*)(&hlds[((w * 8 + ks) * 64 + lane) * 8]);  // rule #20: no A[w]
#pragma unroll
    for (int i = 0; i < 4; ++i) {
      sh8 Bf = *(const sh8*)(w2f + ((ks * 17 + t0 + i) * 64 + lane) * 8);
      acc[0][i] = __builtin_amdgcn_mfma_f32_16x16x32_bf16(A0, Bf, acc[0][i], 0, 0, 0);
      acc[1][i] = __builtin_amdgcn_mfma_f32_16x16x32_bf16(A1, Bf, acc[1][i], 0, 0, 0);
      acc[2][i] = __builtin_amdgcn_mfma_f32_16x16x32_bf16(A2, Bf, acc[2][i], 0, 0, 0);
      acc[3][i] = __builtin_amdgcn_mfma_f32_16x16x32_bf16(A3, Bf, acc[3][i], 0, 0, 0);
    }
    sh8 B16 = *(const sh8*)(w2f + ((ks * 17 + 16) * 64 + lane) * 8);
    acc16 = __builtin_amdgcn_mfma_f32_16x16x32_bf16(A16, B16, acc16, 0, 0, 0);
  }

  // ---- phase 3: relu + masked pool ----
  const float ninv = ninvp[0] + ninvp[1] + ninvp[2] + ninvp[3];
#pragma unroll
  for (int i = 0; i < 4; ++i) {
    const int col = (t0 + i) * 16 + m;       // 0..255, always < EOUT
    const float b2c = b2[col];
    float ssum = 0.f;
#pragma unroll
    for (int mtA = 0; mtA < 4; ++mtA)
#pragma unroll
      for (int r = 0; r < 4; ++r)
        ssum += fmaxf(acc[mtA][i][r] + b2c, 0.f);
    ssum += __shfl_xor(ssum, 16, 64);
    ssum += __shfl_xor(ssum, 32, 64);
    ssum -= ninv * fmaxf(b2c, 0.f);          // invalid agents contribute relu(b2)
    if (q == 0) so288[bg * XPAD + CAR + col] = ssum;
  }
  // tile 16 (cols 256..271): per-wave partial over its 16 agents
  {
    const int colc = 256 + m;
    const float b2c = (colc < EOUT) ? b2[colc] : 0.f;
    float s16 = 0.f;
#pragma unroll
    for (int r = 0; r < 4; ++r)
      s16 += fmaxf(acc16[r] + b2c, 0.f);
    s16 += __shfl_xor(s16, 16, 64);
    s16 += __shfl_xor(s16, 32, 64);
    if (q == 0) t16[w][m] = s16;
  }
  __syncthreads();
  if (w == 0 && q == 0) {
    const int colc = 256 + m;
    const float b2c = (colc < EOUT) ? b2[colc] : 0.f;
    const float tot = t16[0][m] + t16[1][m] + t16[2][m] + t16[3][m]
                    - ninv * fmaxf(b2c, 0.f);  // pad cols: all terms 0
    so288[bg * XPAD + CAR + colc] = tot;
  }
}

// ---------------------------------------------------------------------------
// K2: Q-head, MFMA. 4 waves, 32 batch rows per block (unchanged, ~13 us).
// ---------------------------------------------------------------------------
__global__ __launch_bounds__(256, 2)
void k_q(const float* __restrict__ so288, const short* __restrict__ w3f,
         const float* __restrict__ Qb1, const short* __restrict__ wq2f,
         const float* __restrict__ Qb2, float* __restrict__ out, int B) {
  __shared__ __align__(16) short xf[2 * 9 * 64 * 8];  // 36 KB, [mt][ks][lane][j]
  __shared__ __align__(16) float H[32 * 260];          // 33.3 KB
  const int tid = threadIdx.x;
  const int w = tid >> 6, lane = tid & 63;
  const int q = lane >> 4, m = lane & 15;
  const int b0 = blockIdx.x * 32;

  // ---- stage X ----
#pragma unroll
  for (int it = 0; it < 5; ++it) {
    int sidx = tid + it * 256;               // = (mt*9+ks)*64 + l
    if (sidx < 1152) {
      int mt = sidx / 576, rem = sidx % 576;
      int ks = rem >> 6, l = rem & 63;
      int lq = l >> 4, lm = l & 15;
      int row = b0 + mt * 16 + lm; if (row >= B) row = B - 1;
      const float* xp = so288 + (size_t)row * XPAD + ks * 32 + lq * 8;
      float4 xa = ((const float4*)xp)[0], xb = ((const float4*)xp)[1];
      int4 t = {(int)f2bf2(xa.x, xa.y), (int)f2bf2(xa.z, xa.w),
                (int)f2bf2(xb.x, xb.y), (int)f2bf2(xb.z, xb.w)};
      *(int4*)(xf + sidx * 8) = t;
    }
  }
  __syncthreads();

  // ---- GEMM1: X(32x288) @ Qw1 -> H ----
  f32x4 acc1[2][4];
#pragma unroll
  for (int mt = 0; mt < 2; ++mt)
#pragma unroll
    for (int i = 0; i < 4; ++i) {
      f32x4 z = {0.f, 0.f, 0.f, 0.f};
      acc1[mt][i] = z;
    }
#pragma unroll
  for (int ks = 0; ks < 9; ++ks) {
    sh8 A0 = *(const sh8*)(xf + ((0 * 9 + ks) * 64 + lane) * 8);
    sh8 A1 = *(const sh8*)(xf + ((1 * 9 + ks) * 64 + lane) * 8);
#pragma unroll
    for (int i = 0; i < 4; ++i) {
      sh8 Bf = *(const sh8*)(w3f + ((ks * 16 + 4 * w + i) * 64 + lane) * 8);
      acc1[0][i] = __builtin_amdgcn_mfma_f32_16x16x32_bf16(A0, Bf, acc1[0][i], 0, 0, 0);
      acc1[1][i] = __builtin_amdgcn_mfma_f32_16x16x32_bf16(A1, Bf, acc1[1][i], 0, 0, 0);
    }
  }
#pragma unroll
  for (int i = 0; i < 4; ++i) {
    const int hcol = (4 * w + i) * 16 + m;
    const float bq = Qb1[hcol];
#pragma unroll
    for (int mt = 0; mt < 2; ++mt)
#pragma unroll
      for (int r = 0; r < 4; ++r)
        H[(mt * 16 + q * 4 + r) * 260 + hcol] = fmaxf(acc1[mt][i][r] + bq, 0.f);
  }
  __syncthreads();

  // ---- GEMM2: H(32x256) @ Qw2 -> out ----
  const int mt2 = w >> 1, nt2 = w & 1;
  f32x4 acc2 = {0.f, 0.f, 0.f, 0.f};
#pragma unroll
  for (int ks = 0; ks < 8; ++ks) {
    const float* hp = H + (mt2 * 16 + m) * 260 + ks * 32 + q * 8;
    float4 ha = ((const float4*)hp)[0], hb = ((const float4*)hp)[1];
    int4 t = {(int)f2bf2(ha.x, ha.y), (int)f2bf2(ha.z, ha.w),
              (int)f2bf2(hb.x, hb.y), (int)f2bf2(hb.z, hb.w)};
    sh8 A2 = __builtin_bit_cast(sh8, t);
    sh8 Bf = *(const sh8*)(wq2f + ((ks * 2 + nt2) * 64 + lane) * 8);
    acc2 = __builtin_amdgcn_mfma_f32_16x16x32_bf16(A2, Bf, acc2, 0, 0, 0);
  }
  const int act = nt2 * 16 + m;
  if (act < ADIM) {
    const float bq = Qb2[act];
#pragma unroll
    for (int r = 0; r < 4; ++r) {
      const int row = b0 + mt2 * 16 + q * 4 + r;
      if (row < B) out[(size_t)row * ADIM + act] = acc2[r] + bq;
    }
  }
}

extern "C" void kernel_launch(void* const* d_in, const int* in_sizes, int n_in,
                              void* d_out, int out_size, void* d_ws, size_t ws_size,
                              hipStream_t stream) {
  const float* s   = (const float*)d_in[0];
  const float* W1  = (const float*)d_in[1];
  const float* b1  = (const float*)d_in[2];
  const float* W2  = (const float*)d_in[3];
  const float* b2  = (const float*)d_in[4];
  const float* Qw1 = (const float*)d_in[5];
  const float* Qb1 = (const float*)d_in[6];
  const float* Qw2 = (const float*)d_in[7];
  const float* Qb2 = (const float*)d_in[8];
  float* out = (float*)d_out;
  const int B = in_sizes[0] / SROW;

  // ws: [so288: B*288 f32][w1f 8192][w2f 69632][w3f 73728][wq2f 8192] bf16
  char* wsb = (char*)d_ws;
  float* so288 = (float*)wsb;
  size_t off = (size_t)B * XPAD * sizeof(float);
  short* w1f  = (short*)(wsb + off);            off += 8192 * 2;
  short* w2f  = (short*)(wsb + off);            off += 69632 * 2;
  short* w3f  = (short*)(wsb + off);            off += 73728 * 2;
  short* wq2f = (short*)(wsb + off);

  const int prep_elems = 8192 + 69632 + 73728 + 8192;
  k_prep<<<(prep_elems + 255) / 256, 256, 0, stream>>>(W1, b1, W2, Qw1, Qw2,
                                                       w1f, w2f, w3f, wq2f);
  k_enc<<<B, 256, 0, stream>>>(s, w1f, w2f, b2, so288, B);
  k_q<<<(B + 31) / 32, 256, 0, stream>>>(so288, w3f, Qb1, wq2f, Qb2, out, B);
}

// Round 2
// 160.568 us; speedup vs baseline: 1.0831x; 1.0831x over previous
//
#include <hip/hip_runtime.h>

#define CAR 8
#define SROW 520   // CAR + 64*CAR
#define HID 256
#define EOUT 257
#define XPAD 288   // padded Q-input row: 8 self + 257 enc + pad, 9 k-steps of 32
#define ADIM 30

typedef __attribute__((ext_vector_type(8))) short sh8;
typedef __attribute__((ext_vector_type(4))) float f32x4;

__device__ __forceinline__ short f2bf(float f) {
  unsigned u = __builtin_bit_cast(unsigned, f);
  u += 0x7fffu + ((u >> 16) & 1u);   // RNE
  return (short)(u >> 16);
}
// pack two fp32 -> packed bf16x2 (RNE, 5 VALU)
__device__ __forceinline__ unsigned f2bf2(float a, float b) {
  unsigned ua = __builtin_bit_cast(unsigned, a);
  ua += 0x7fffu + ((ua >> 16) & 1u);
  unsigned ub = __builtin_bit_cast(unsigned, b);
  ub += 0x7fffu + ((ub >> 16) & 1u);
  return __builtin_amdgcn_perm(ub, ua, 0x07060302);  // [a.hi16 | b.hi16]
}
// pack two fp32 -> packed bf16x2 (TRUNC, 1 VALU) — used for h staging only
__device__ __forceinline__ unsigned pkt(float a, float b) {
  return __builtin_amdgcn_perm(__builtin_bit_cast(unsigned, b),
                               __builtin_bit_cast(unsigned, a), 0x07060302);
}

// ---------------------------------------------------------------------------
// Prep: swizzle all weights to bf16 MFMA fragments. (unchanged)
// w1f : [W1;b1]^T as A [16 mt][64][8]  k=0..7 -> W1 row, k=8 -> b1   (8192)
// w2f : W2  as B   [8 ks][17 nt][64][8]               (69632)  stride/ks = 8704!
// w3f : Qw1 as B   [9 ks][16 nt][64][8], k=X-row idx  (73728)
// wq2f: Qw2 as B   [8 ks][2 nt][64][8]                (8192)
// ---------------------------------------------------------------------------
__global__ void k_prep(const float* __restrict__ W1, const float* __restrict__ b1,
                       const float* __restrict__ W2,
                       const float* __restrict__ Qw1, const float* __restrict__ Qw2,
                       short* __restrict__ w1f, short* __restrict__ w2f,
                       short* __restrict__ w3f, short* __restrict__ wq2f) {
  int idx = blockIdx.x * 256 + threadIdx.x;
  if (idx < 8192) {                         // [W1;b1]^T as A
    int mt = idx >> 9, r = idx & 511, lane = r >> 3, j = r & 7;
    int quad = lane >> 4, m = lane & 15;
    int hid = mt * 16 + m;
    float v = (quad == 0) ? W1[j * HID + hid]
            : (quad == 1 && j == 0) ? b1[hid] : 0.0f;   // k=8 row = b1
    w1f[idx] = f2bf(v);
    return;
  }
  int i2 = idx - 8192;
  if (i2 < 69632) {                         // W2 as B (ks stride = 17*512 = 8704)
    int ks = i2 / 8704, r = i2 % 8704;
    int nt = r >> 9, r2 = r & 511, lane = r2 >> 3, j = r2 & 7;
    int quad = lane >> 4, m = lane & 15;
    int k = ks * 32 + quad * 8 + j, n = nt * 16 + m;
    float v = (n < EOUT) ? W2[k * EOUT + n] : 0.0f;
    w2f[i2] = f2bf(v);
    return;
  }
  int i3 = i2 - 69632;
  if (i3 < 73728) {                         // Qw1 as B (k indexes padded X row)
    int ks = i3 >> 13, r = i3 & 8191;
    int nt = r >> 9, r2 = r & 511, lane = r2 >> 3, j = r2 & 7;
    int quad = lane >> 4, m = lane & 15;
    int k = ks * 32 + quad * 8 + j, n = nt * 16 + m;
    float v = (k < 265) ? Qw1[k * HID + n] : 0.0f;
    w3f[i3] = f2bf(v);
    return;
  }
  int i4 = i3 - 73728;
  if (i4 < 8192) {                          // Qw2 as B
    int ks = i4 >> 10, r = i4 & 1023;
    int nt = r >> 9, r2 = r & 511, lane = r2 >> 3, j = r2 & 7;
    int quad = lane >> 4, m = lane & 15;
    int k = ks * 32 + quad * 8 + j, n = nt * 16 + m;
    float v = (n < ADIM) ? Qw2[k * ADIM + n] : 0.0f;
    wq2f[i4] = f2bf(v);
  }
}

// ---------------------------------------------------------------------------
// K1: fused encoder + pool. NB=2 batch elems per block, 8 waves (512 thr).
// Combines R0's amortization (both elems share every B-fragment) with R1's
// occupancy: LDS 64.5 KB -> 2 blocks/CU, __launch_bounds__(512,4) caps
// VGPR<=128 -> 4 waves/SIMD. Per-wave phase 2 = 2 N-tiles x 4 mtA x 2 e x
// 8 ks = 128 MFMA + 8 tile16 = 136, perfectly balanced (tile 16 split one
// (elem, agent-group) slice per wave, acc = 68 floats).
// Wave w: elem we=w>>2, agent group g=w&3.
// ---------------------------------------------------------------------------
__global__ __launch_bounds__(512, 4)
void k_enc(const float* __restrict__ s, const short* __restrict__ w1f,
           const short* __restrict__ w2f, const float* __restrict__ b2,
           float* __restrict__ so288, int B) {
  __shared__ __align__(16) short hlds[2][16384];  // 64 KB: [e][(g*8+ks)*64+slot]*8+j
  __shared__ float ninvp[8];
  __shared__ float t16[8][16];

  const int tid = threadIdx.x;
  const int w = tid >> 6, lane = tid & 63;
  const int q = lane >> 4, m = lane & 15;
  const int we = w >> 2, g = w & 3;
  const size_t bg0 = 2 * (size_t)blockIdx.x;
  size_t bg = bg0 + we; if (bg >= (size_t)B) bg = B - 1;

  // ---- phase 1: h = relu([surr,1]@[W1;b1]) for 16 agents (g) of elem we ----
  const float* srow0 = s + bg * SROW + CAR;
  int4 pk = {0, 0, 0, 0};
  bool inv = false;
  if (lane < 16) {                           // agent = 16*g + lane
    const float* sr = srow0 + (g * 16 + lane) * CAR;
    float4 f0 = ((const float4*)sr)[0], f1 = ((const float4*)sr)[1];
    inv = (f0.x == -1.f) | (f0.y == -1.f) | (f0.z == -1.f) | (f0.w == -1.f) |
          (f1.x == -1.f) | (f1.y == -1.f) | (f1.z == -1.f) | (f1.w == -1.f);
    if (!inv) {                              // mask folded at source
      pk.x = (int)f2bf2(f0.x, f0.y); pk.y = (int)f2bf2(f0.z, f0.w);
      pk.z = (int)f2bf2(f1.x, f1.y); pk.w = (int)f2bf2(f1.z, f1.w);
    }
  }
  const float vflag = inv ? 0.f : 1.f;
  unsigned long long bal = __ballot(inv);
  if (lane == 0) ninvp[w] = (float)__popcll(bal);

  if (w == 1 || w == 2) {                    // self-state + tail pad per elem
    size_t rr = bg0 + (w - 1); if (rr >= (size_t)B) rr = B - 1;
    if (lane < CAR)       so288[rr * XPAD + lane] = s[rr * SROW + lane];
    else if (lane < 16)   so288[rr * XPAD + 280 + (lane - 8)] = 0.f;
  }

  int4 p0;
  p0.x = __shfl(pk.x, m, 64); p0.y = __shfl(pk.y, m, 64);
  p0.z = __shfl(pk.z, m, 64); p0.w = __shfl(pk.w, m, 64);
  const float vv0 = __shfl(vflag, m, 64);
  if (q == 1) {                              // k=8 constant-1 column (masked)
    p0.x = (vv0 != 0.f) ? 0x3f80 : 0; p0.y = p0.z = p0.w = 0;
  } else if (q >= 2) {
    p0.x = p0.y = p0.z = p0.w = 0;
  }
  sh8 bs = __builtin_bit_cast(sh8, p0);

#pragma unroll 4
  for (int mt = 0; mt < 16; ++mt) {
    sh8 af = *(const sh8*)(w1f + (mt * 64 + lane) * 8);
    f32x4 z = {0.f, 0.f, 0.f, 0.f};
    f32x4 c0 = __builtin_amdgcn_mfma_f32_16x16x32_bf16(af, bs, z, 0, 0, 0);
    const int hidb = mt * 16 + q * 4;
    const int ks = hidb >> 5, qB = (hidb >> 3) & 3, js = hidb & 7;
    uint2 k0;
    k0.x = pkt(fmaxf(c0[0], 0.f), fmaxf(c0[1], 0.f));
    k0.y = pkt(fmaxf(c0[2], 0.f), fmaxf(c0[3], 0.f));
    *(uint2*)(&hlds[we][((g * 8 + ks) * 64 + qB * 16 + m) * 8 + js]) = k0;
  }
  __syncthreads();

  // ---- phase 2: enc = h @ W2, tiles {2w, 2w+1} for both elems + tile16 slice
  f32x4 acc[4][2][2];                        // [mtA][i][e]
  f32x4 acc16 = {0.f, 0.f, 0.f, 0.f};
#pragma unroll
  for (int mtA = 0; mtA < 4; ++mtA)
#pragma unroll
    for (int i = 0; i < 2; ++i)
#pragma unroll
      for (int e = 0; e < 2; ++e) {
        f32x4 z = {0.f, 0.f, 0.f, 0.f};
        acc[mtA][i][e] = z;
      }
  const int t0 = 2 * w;
#pragma unroll
  for (int ks = 0; ks < 8; ++ks) {
    sh8 B0  = *(const sh8*)(w2f + ((ks * 17 + t0)     * 64 + lane) * 8);
    sh8 B1  = *(const sh8*)(w2f + ((ks * 17 + t0 + 1) * 64 + lane) * 8);
    sh8 B16 = *(const sh8*)(w2f + ((ks * 17 + 16)     * 64 + lane) * 8);
    sh8 A16 = *(const sh8*)(&hlds[we][((g * 8 + ks) * 64 + lane) * 8]);
    acc16 = __builtin_amdgcn_mfma_f32_16x16x32_bf16(A16, B16, acc16, 0, 0, 0);
#pragma unroll
    for (int e = 0; e < 2; ++e) {
      sh8 A0 = *(const sh8*)(&hlds[e][((0 * 8 + ks) * 64 + lane) * 8]);
      sh8 A1 = *(const sh8*)(&hlds[e][((1 * 8 + ks) * 64 + lane) * 8]);
      sh8 A2 = *(const sh8*)(&hlds[e][((2 * 8 + ks) * 64 + lane) * 8]);
      sh8 A3 = *(const sh8*)(&hlds[e][((3 * 8 + ks) * 64 + lane) * 8]);
      acc[0][0][e] = __builtin_amdgcn_mfma_f32_16x16x32_bf16(A0, B0, acc[0][0][e], 0, 0, 0);
      acc[1][0][e] = __builtin_amdgcn_mfma_f32_16x16x32_bf16(A1, B0, acc[1][0][e], 0, 0, 0);
      acc[2][0][e] = __builtin_amdgcn_mfma_f32_16x16x32_bf16(A2, B0, acc[2][0][e], 0, 0, 0);
      acc[3][0][e] = __builtin_amdgcn_mfma_f32_16x16x32_bf16(A3, B0, acc[3][0][e], 0, 0, 0);
      acc[0][1][e] = __builtin_amdgcn_mfma_f32_16x16x32_bf16(A0, B1, acc[0][1][e], 0, 0, 0);
      acc[1][1][e] = __builtin_amdgcn_mfma_f32_16x16x32_bf16(A1, B1, acc[1][1][e], 0, 0, 0);
      acc[2][1][e] = __builtin_amdgcn_mfma_f32_16x16x32_bf16(A2, B1, acc[2][1][e], 0, 0, 0);
      acc[3][1][e] = __builtin_amdgcn_mfma_f32_16x16x32_bf16(A3, B1, acc[3][1][e], 0, 0, 0);
    }
  }

  // ---- phase 3: relu + masked pool ----
  const float ninv[2] = {ninvp[0] + ninvp[1] + ninvp[2] + ninvp[3],
                         ninvp[4] + ninvp[5] + ninvp[6] + ninvp[7]};
#pragma unroll
  for (int i = 0; i < 2; ++i) {
    const int col = (t0 + i) * 16 + m;       // 0..255, always < EOUT
    const float b2c = b2[col];
    const float rb2 = fmaxf(b2c, 0.f);
#pragma unroll
    for (int e = 0; e < 2; ++e) {
      float ssum = 0.f;
#pragma unroll
      for (int mtA = 0; mtA < 4; ++mtA)
#pragma unroll
        for (int r = 0; r < 4; ++r)
          ssum += fmaxf(acc[mtA][i][e][r] + b2c, 0.f);
      ssum += __shfl_xor(ssum, 16, 64);
      ssum += __shfl_xor(ssum, 32, 64);
      ssum -= ninv[e] * rb2;                 // invalid agents contribute relu(b2)
      if (q == 0) {
        size_t rr = bg0 + e; if (rr >= (size_t)B) rr = B - 1;
        so288[rr * XPAD + CAR + col] = ssum;
      }
    }
  }
  // tile 16 (cols 256..271): per-wave partial (16 agents of elem we)
  {
    const int colc = 256 + m;
    const float b2c = (colc < EOUT) ? b2[colc] : 0.f;
    float s16 = 0.f;
#pragma unroll
    for (int r = 0; r < 4; ++r)
      s16 += fmaxf(acc16[r] + b2c, 0.f);
    s16 += __shfl_xor(s16, 16, 64);
    s16 += __shfl_xor(s16, 32, 64);
    if (q == 0) t16[w][m] = s16;
  }
  __syncthreads();
  if ((w == 0 || w == 4) && q == 0) {        // wave 0 -> elem 0, wave 4 -> elem 1
    const int e = w >> 2;
    const int colc = 256 + m;
    const float b2c = (colc < EOUT) ? b2[colc] : 0.f;
    const float tot = t16[e * 4 + 0][m] + t16[e * 4 + 1][m] +
                      t16[e * 4 + 2][m] + t16[e * 4 + 3][m]
                    - ninv[e] * fmaxf(b2c, 0.f);  // pad cols: all terms 0
    size_t rr = bg0 + e; if (rr >= (size_t)B) rr = B - 1;
    so288[rr * XPAD + CAR + colc] = tot;
  }
}

// ---------------------------------------------------------------------------
// K2: Q-head, MFMA. 4 waves, 32 batch rows per block (unchanged, ~13 us).
// ---------------------------------------------------------------------------
__global__ __launch_bounds__(256, 2)
void k_q(const float* __restrict__ so288, const short* __restrict__ w3f,
         const float* __restrict__ Qb1, const short* __restrict__ wq2f,
         const float* __restrict__ Qb2, float* __restrict__ out, int B) {
  __shared__ __align__(16) short xf[2 * 9 * 64 * 8];  // 36 KB, [mt][ks][lane][j]
  __shared__ __align__(16) float H[32 * 260];          // 33.3 KB
  const int tid = threadIdx.x;
  const int w = tid >> 6, lane = tid & 63;
  const int q = lane >> 4, m = lane & 15;
  const int b0 = blockIdx.x * 32;

  // ---- stage X ----
#pragma unroll
  for (int it = 0; it < 5; ++it) {
    int sidx = tid + it * 256;               // = (mt*9+ks)*64 + l
    if (sidx < 1152) {
      int mt = sidx / 576, rem = sidx % 576;
      int ks = rem >> 6, l = rem & 63;
      int lq = l >> 4, lm = l & 15;
      int row = b0 + mt * 16 + lm; if (row >= B) row = B - 1;
      const float* xp = so288 + (size_t)row * XPAD + ks * 32 + lq * 8;
      float4 xa = ((const float4*)xp)[0], xb = ((const float4*)xp)[1];
      int4 t = {(int)f2bf2(xa.x, xa.y), (int)f2bf2(xa.z, xa.w),
                (int)f2bf2(xb.x, xb.y), (int)f2bf2(xb.z, xb.w)};
      *(int4*)(xf + sidx * 8) = t;
    }
  }
  __syncthreads();

  // ---- GEMM1: X(32x288) @ Qw1 -> H ----
  f32x4 acc1[2][4];
#pragma unroll
  for (int mt = 0; mt < 2; ++mt)
#pragma unroll
    for (int i = 0; i < 4; ++i) {
      f32x4 z = {0.f, 0.f, 0.f, 0.f};
      acc1[mt][i] = z;
    }
#pragma unroll
  for (int ks = 0; ks < 9; ++ks) {
    sh8 A0 = *(const sh8*)(xf + ((0 * 9 + ks) * 64 + lane) * 8);
    sh8 A1 = *(const sh8*)(xf + ((1 * 9 + ks) * 64 + lane) * 8);
#pragma unroll
    for (int i = 0; i < 4; ++i) {
      sh8 Bf = *(const sh8*)(w3f + ((ks * 16 + 4 * w + i) * 64 + lane) * 8);
      acc1[0][i] = __builtin_amdgcn_mfma_f32_16x16x32_bf16(A0, Bf, acc1[0][i], 0, 0, 0);
      acc1[1][i] = __builtin_amdgcn_mfma_f32_16x16x32_bf16(A1, Bf, acc1[1][i], 0, 0, 0);
    }
  }
#pragma unroll
  for (int i = 0; i < 4; ++i) {
    const int hcol = (4 * w + i) * 16 + m;
    const float bq = Qb1[hcol];
#pragma unroll
    for (int mt = 0; mt < 2; ++mt)
#pragma unroll
      for (int r = 0; r < 4; ++r)
        H[(mt * 16 + q * 4 + r) * 260 + hcol] = fmaxf(acc1[mt][i][r] + bq, 0.f);
  }
  __syncthreads();

  // ---- GEMM2: H(32x256) @ Qw2 -> out ----
  const int mt2 = w >> 1, nt2 = w & 1;
  f32x4 acc2 = {0.f, 0.f, 0.f, 0.f};
#pragma unroll
  for (int ks = 0; ks < 8; ++ks) {
    const float* hp = H + (mt2 * 16 + m) * 260 + ks * 32 + q * 8;
    float4 ha = ((const float4*)hp)[0], hb = ((const float4*)hp)[1];
    int4 t = {(int)f2bf2(ha.x, ha.y), (int)f2bf2(ha.z, ha.w),
              (int)f2bf2(hb.x, hb.y), (int)f2bf2(hb.z, hb.w)};
    sh8 A2 = __builtin_bit_cast(sh8, t);
    sh8 Bf = *(const sh8*)(wq2f + ((ks * 2 + nt2) * 64 + lane) * 8);
    acc2 = __builtin_amdgcn_mfma_f32_16x16x32_bf16(A2, Bf, acc2, 0, 0, 0);
  }
  const int act = nt2 * 16 + m;
  if (act < ADIM) {
    const float bq = Qb2[act];
#pragma unroll
    for (int r = 0; r < 4; ++r) {
      const int row = b0 + mt2 * 16 + q * 4 + r;
      if (row < B) out[(size_t)row * ADIM + act] = acc2[r] + bq;
    }
  }
}

extern "C" void kernel_launch(void* const* d_in, const int* in_sizes, int n_in,
                              void* d_out, int out_size, void* d_ws, size_t ws_size,
                              hipStream_t stream) {
  const float* s   = (const float*)d_in[0];
  const float* W1  = (const float*)d_in[1];
  const float* b1  = (const float*)d_in[2];
  const float* W2  = (const float*)d_in[3];
  const float* b2  = (const float*)d_in[4];
  const float* Qw1 = (const float*)d_in[5];
  const float* Qb1 = (const float*)d_in[6];
  const float* Qw2 = (const float*)d_in[7];
  const float* Qb2 = (const float*)d_in[8];
  float* out = (float*)d_out;
  const int B = in_sizes[0] / SROW;

  // ws: [so288: B*288 f32][w1f 8192][w2f 69632][w3f 73728][wq2f 8192] bf16
  char* wsb = (char*)d_ws;
  float* so288 = (float*)wsb;
  size_t off = (size_t)B * XPAD * sizeof(float);
  short* w1f  = (short*)(wsb + off);            off += 8192 * 2;
  short* w2f  = (short*)(wsb + off);            off += 69632 * 2;
  short* w3f  = (short*)(wsb + off);            off += 73728 * 2;
  short* wq2f = (short*)(wsb + off);

  const int prep_elems = 8192 + 69632 + 73728 + 8192;
  k_prep<<<(prep_elems + 255) / 256, 256, 0, stream>>>(W1, b1, W2, Qw1, Qw2,
                                                       w1f, w2f, w3f, wq2f);
  k_enc<<<(B + 1) / 2, 512, 0, stream>>>(s, w1f, w2f, b2, so288, B);
  k_q<<<(B + 31) / 32, 256, 0, stream>>>(so288, w3f, Qb1, wq2f, Qb2, out, B);
}